// Round 8
// baseline (102.733 us; speedup 1.0000x reference)
//
#include <hip/hip_runtime.h>

#define BATCH 8
#define CHN 128
#define HH 160
#define WW 160
#define HW (HH*WW)
#define RR 2
#define MAXOFF 5
#define NOFF 25
#define TW 32
#define TH 8
#define PW (TW + 2*RR)     /* 36 */
#define PH (TH + 2*RR)     /* 12 */
#define NG 4               /* channel groups per block */
#define CPG (CHN/NG)       /* 32 channels per group */
#define RC 2               /* channels per group per round */
#define SCH (NG*RC)        /* 8 staged channels per round */
#define ROUNDS (CPG/RC)    /* 16 */
#define NPT 64             /* pixel-threads per group (4 px each) */
#define NTHREADS 256
#define CHFL (PH*PW)       /* 432 floats per staged channel */
#define STFL (SCH*CHFL)    /* 3456 floats staged per round */
#define NSLOT 14           /* ceil(STFL/NTHREADS) */
#define OCH 4              /* epilogue offset chunk */

__device__ __forceinline__ int reflect_idx(int i, int n) {
    if (i < 0) i = -i;
    if (i >= n) i = 2 * (n - 1) - i;
    return i;
}

__global__ __launch_bounds__(NTHREADS) void costvol_kernel(
    const float* __restrict__ c1,
    const float* __restrict__ c2,
    const float* __restrict__ pw,
    float* __restrict__ out)
{
    __shared__ float lds[STFL];        // 13824 B; epilogue reuses 12288 B

    const int tid = threadIdx.x;
    const int g  = tid >> 6;           // channel group 0..3
    const int pt = tid & (NPT - 1);    // pixel-thread 0..63
    const int xq = pt & 7;             // float4 column 0..7
    const int y  = pt >> 3;            // row 0..7
    const int x0 = xq * 4;

    // XCD-aware swizzle: 800 = 8 XCDs x 100 tiles; XCD k owns batch image k.
    int bidx = (int)blockIdx.x;
    bidx = (bidx & 7) * 100 + (bidx >> 3);
    const int tx0 = (bidx % (WW / TW)) * TW; bidx /= (WW / TW);
    const int ty0 = (bidx % (HH / TH)) * TH; bidx /= (HH / TH);
    const int b = bidx;

    // ---- round-invariant staging byte offsets ----
    int boff[NSLOT];
#pragma unroll
    for (int k = 0; k < NSLOT; ++k) {
        const int idx = tid + k * NTHREADS;
        if (idx < STFL) {
            int c   = idx / CHFL;          // staged slot 0..7
            int rem = idx - c * CHFL;
            int ty  = rem / PW;
            int tx  = rem - ty * PW;
            int gh  = c >> 1, j = c & 1;   // owner group, channel-within-round
            int gr  = reflect_idx(ty0 - RR + ty, HH);
            int gc  = reflect_idx(tx0 - RR + tx, WW);
            boff[k] = ((gh * CPG + j) * HW + gr * WW + gc) * 4;
        } else {
            boff[k] = 0;                   // dead slots (tid>=128 at k=13)
        }
    }

    const char*  c2b = (const char*)(c2 + (size_t)b * CHN * HW);
    const float* c1p = c1 + ((size_t)b * CHN + g * CPG) * HW
                          + (ty0 + y) * WW + tx0 + x0;

    float  sv[NSLOT];     // staged c2 values in flight
    float4 sc[RC], sn[RC];

    auto issue_c2 = [&](int r) {
        const char* base = c2b + (size_t)r * RC * HW * 4;
#pragma unroll
        for (int k = 0; k < NSLOT; ++k)
            if (tid + k * NTHREADS < STFL)
                sv[k] = *(const float*)(base + boff[k]);
    };
    auto write_lds = [&]() {
#pragma unroll
        for (int k = 0; k < NSLOT; ++k)
            if (tid + k * NTHREADS < STFL)
                lds[tid + k * NTHREADS] = sv[k];
    };
    auto issue_c1 = [&](int r, float4* dst) {
#pragma unroll
        for (int j = 0; j < RC; ++j)
            dst[j] = *(const float4*)(c1p + (size_t)(r * RC + j) * HW);
    };

    float4 acc[NOFF];
#pragma unroll
    for (int i = 0; i < NOFF; ++i) acc[i] = make_float4(0.f, 0.f, 0.f, 0.f);

    // ---- prologue: stage round 0, prefetch round 1 ----
    issue_c2(0);
    issue_c1(0, sc);
    write_lds();
    __syncthreads();                   // lds holds round 0
    issue_c2(1);
    issue_c1(1, sn);

    for (int r = 0; r < ROUNDS; ++r) {
        const float* lbase = lds + (g * RC) * CHFL + y * PW + x0;
#pragma unroll
        for (int j = 0; j < RC; ++j) {
            const float4 s = sc[j];
            const float* tb = lbase + j * CHFL;
#pragma unroll
            for (int dy = 0; dy < MAXOFF; ++dy) {
                const float4 wa = *(const float4*)(tb + dy * PW);
                const float4 wb = *(const float4*)(tb + dy * PW + 4);
                const float w0 = wa.x, w1 = wa.y, w2 = wa.z, w3 = wa.w;
                const float w4 = wb.x, w5 = wb.y, w6 = wb.z, w7 = wb.w;
                float4* A = &acc[dy * MAXOFF];
                A[0].x = fmaf(s.x, w0, A[0].x);  A[0].y = fmaf(s.y, w1, A[0].y);
                A[0].z = fmaf(s.z, w2, A[0].z);  A[0].w = fmaf(s.w, w3, A[0].w);
                A[1].x = fmaf(s.x, w1, A[1].x);  A[1].y = fmaf(s.y, w2, A[1].y);
                A[1].z = fmaf(s.z, w3, A[1].z);  A[1].w = fmaf(s.w, w4, A[1].w);
                A[2].x = fmaf(s.x, w2, A[2].x);  A[2].y = fmaf(s.y, w3, A[2].y);
                A[2].z = fmaf(s.z, w4, A[2].z);  A[2].w = fmaf(s.w, w5, A[2].w);
                A[3].x = fmaf(s.x, w3, A[3].x);  A[3].y = fmaf(s.y, w4, A[3].y);
                A[3].z = fmaf(s.z, w5, A[3].z);  A[3].w = fmaf(s.w, w6, A[3].w);
                A[4].x = fmaf(s.x, w4, A[4].x);  A[4].y = fmaf(s.y, w5, A[4].y);
                A[4].z = fmaf(s.z, w6, A[4].z);  A[4].w = fmaf(s.w, w7, A[4].w);
            }
        }
        __syncthreads();               // everyone done reading lds (round r)
        if (r + 1 < ROUNDS) {
            write_lds();               // waits on round r+1's loads, writes them
#pragma unroll
            for (int j = 0; j < RC; ++j) sc[j] = sn[j];
            __syncthreads();           // lds holds round r+1
            if (r + 2 < ROUNDS) {
                issue_c2(r + 2);       // overlap with next compute
                issue_c1(r + 2, sn);
            }
        }
    }

    // ---- cross-group reduction (g1..g3 -> g0) + scale + PReLU + store ----
    const float a = pw[0];
    const float inv_c = 1.0f / (float)CHN;
    float4* e4 = (float4*)lds;         // 3 * OCH * 64 * 16B = 12288 B

    for (int o0 = 0; o0 < NOFF; o0 += OCH) {
        const int K = (NOFF - o0) < OCH ? (NOFF - o0) : OCH;
        __syncthreads();
        if (g > 0) {
#pragma unroll
            for (int k = 0; k < OCH; ++k)
                if (k < K)
                    e4[((g - 1) * OCH + k) * NPT + pt] = acc[o0 + k];
        }
        __syncthreads();
        if (g == 0) {
#pragma unroll
            for (int k = 0; k < OCH; ++k) {
                if (k < K) {
                    const int o = o0 + k;
                    float4 v  = acc[o];
                    float4 v1 = e4[(0 * OCH + k) * NPT + pt];
                    float4 v2 = e4[(1 * OCH + k) * NPT + pt];
                    float4 v3 = e4[(2 * OCH + k) * NPT + pt];
                    float rx = (v.x + v1.x + v2.x + v3.x) * inv_c;
                    float ry = (v.y + v1.y + v2.y + v3.y) * inv_c;
                    float rz = (v.z + v1.z + v2.z + v3.z) * inv_c;
                    float rw = (v.w + v1.w + v2.w + v3.w) * inv_c;
                    rx = (rx >= 0.f) ? rx : a * rx;
                    ry = (ry >= 0.f) ? ry : a * ry;
                    rz = (rz >= 0.f) ? rz : a * rz;
                    rw = (rw >= 0.f) ? rw : a * rw;
                    *(float4*)(out + (size_t)(b * NOFF + o) * HW
                               + (ty0 + y) * WW + tx0 + x0)
                        = make_float4(rx, ry, rz, rw);
                }
            }
        }
    }
}

extern "C" void kernel_launch(void* const* d_in, const int* in_sizes, int n_in,
                              void* d_out, int out_size, void* d_ws, size_t ws_size,
                              hipStream_t stream) {
    const float* c1 = (const float*)d_in[0];
    const float* c2 = (const float*)d_in[1];
    const float* pw = (const float*)d_in[2];
    float* out = (float*)d_out;

    dim3 grid((WW / TW) * (HH / TH) * BATCH);   // 5*20*8 = 800 blocks
    dim3 block(NTHREADS);
    costvol_kernel<<<grid, block, 0, stream>>>(c1, c2, pw, out);
}

// Round 9
// 54.461 us; speedup vs baseline: 1.8864x; 1.8864x over previous
//
#include <hip/hip_runtime.h>

#define BATCH 8
#define CHN 128
#define HH 160
#define WW 160
#define HW (HH*WW)
#define RR 2
#define MAXOFF 5
#define NOFF 25
#define TW 32
#define TH 8
#define PW (TW + 2*RR)     /* 36 */
#define PH (TH + 2*RR)     /* 12 */
#define NG 4               /* channel groups per block */
#define CPG (CHN/NG)       /* 32 channels per group */
#define RC 2               /* channels per group per round */
#define SCH (NG*RC)        /* 8 staged channels per round */
#define ROUNDS (CPG/RC)    /* 16 */
#define NPT 64             /* threads per group: 16 xh x 4 yg (2 rows each) */
#define NTHREADS 256
#define CHFL (PH*PW)       /* 432 floats per staged channel */
#define STFL (SCH*CHFL)    /* 3456 floats staged per round */
#define NSLOT 14           /* ceil(STFL/NTHREADS) */
#define OCH 4              /* epilogue offset chunk */

__device__ __forceinline__ int reflect_idx(int i, int n) {
    if (i < 0) i = -i;
    if (i >= n) i = 2 * (n - 1) - i;
    return i;
}

__global__ __launch_bounds__(NTHREADS) void costvol_kernel(
    const float* __restrict__ c1,
    const float* __restrict__ c2,
    const float* __restrict__ pw,
    float* __restrict__ out)
{
    __shared__ float lds[STFL];        // 13824 B

    const int tid = threadIdx.x;
    const int g  = tid >> 6;           // channel group 0..3
    const int pt = tid & (NPT - 1);    // 0..63
    const int xh = pt & 15;            // float2 column 0..15
    const int yg = pt >> 4;            // row-pair 0..3 -> rows 2yg, 2yg+1

    // XCD-aware swizzle: 800 = 8 XCDs x 100 tiles; XCD k owns batch image k.
    int bidx = (int)blockIdx.x;
    bidx = (bidx & 7) * 100 + (bidx >> 3);
    const int tx0 = (bidx % (WW / TW)) * TW; bidx /= (WW / TW);
    const int ty0 = (bidx % (HH / TH)) * TH; bidx /= (HH / TH);
    const int b = bidx;

    // ---- round-invariant staging byte offsets ----
    int boff[NSLOT];
#pragma unroll
    for (int k = 0; k < NSLOT; ++k) {
        const int idx = tid + k * NTHREADS;
        if (idx < STFL) {
            int c   = idx / CHFL;          // staged slot 0..7
            int rem = idx - c * CHFL;
            int ty  = rem / PW;
            int tx  = rem - ty * PW;
            int gh  = c >> 1, j = c & 1;   // owner group, channel-within-round
            int gr  = reflect_idx(ty0 - RR + ty, HH);
            int gc  = reflect_idx(tx0 - RR + tx, WW);
            boff[k] = ((gh * CPG + j) * HW + gr * WW + gc) * 4;
        } else {
            boff[k] = 0;
        }
    }

    const char*  c2b = (const char*)(c2 + (size_t)b * CHN * HW);
    const float* c1p = c1 + ((size_t)b * CHN + g * CPG) * HW
                          + (ty0 + 2 * yg) * WW + tx0 + xh * 2;

    float  sv[NSLOT];                  // staged c2 values in flight
    float2 sc0[RC], sc1[RC], sn0[RC], sn1[RC];   // c1 rows 0/1, cur/next

    auto issue_c2 = [&](int r) {
        const char* base = c2b + (size_t)r * RC * HW * 4;
#pragma unroll
        for (int k = 0; k < NSLOT; ++k)
            if (tid + k * NTHREADS < STFL)
                sv[k] = *(const float*)(base + boff[k]);
    };
    auto write_lds = [&]() {
#pragma unroll
        for (int k = 0; k < NSLOT; ++k)
            if (tid + k * NTHREADS < STFL)
                lds[tid + k * NTHREADS] = sv[k];
    };
    auto issue_c1 = [&](int r, float2* d0, float2* d1) {
#pragma unroll
        for (int j = 0; j < RC; ++j) {
            d0[j] = *(const float2*)(c1p + (size_t)(r * RC + j) * HW);
            d1[j] = *(const float2*)(c1p + (size_t)(r * RC + j) * HW + WW);
        }
    };

    float2 acc0[NOFF], acc1[NOFF];     // 100 VGPRs
#pragma unroll
    for (int i = 0; i < NOFF; ++i) {
        acc0[i] = make_float2(0.f, 0.f);
        acc1[i] = make_float2(0.f, 0.f);
    }

    // ---- prologue: stage round 0, prefetch round 1 ----
    issue_c2(0);
    issue_c1(0, sc0, sc1);
    write_lds();
    __syncthreads();                   // lds holds round 0
    issue_c2(1);
    issue_c1(1, sn0, sn1);

    for (int r = 0; r < ROUNDS; ++r) {
        // compute round r: 2 channels x 2 rows x 25 offsets
        const float* lbase = lds + (g * RC) * CHFL + (2 * yg) * PW + xh * 2;
#pragma unroll
        for (int j = 0; j < RC; ++j) {
            const float* tb = lbase + j * CHFL;
            // 6 row-windows (rows 2yg .. 2yg+5), 3 float2 each
            float2 wr[6][3];
#pragma unroll
            for (int dr = 0; dr < 6; ++dr) {
                wr[dr][0] = *(const float2*)(tb + dr * PW);
                wr[dr][1] = *(const float2*)(tb + dr * PW + 2);
                wr[dr][2] = *(const float2*)(tb + dr * PW + 4);
            }
            const float2 s0 = sc0[j];
            const float2 s1 = sc1[j];
#pragma unroll
            for (int dy = 0; dy < MAXOFF; ++dy) {
                {   // output row 0 uses window row dy
                    const float2 w0 = wr[dy][0], w1 = wr[dy][1], w2 = wr[dy][2];
                    float2* A = &acc0[dy * MAXOFF];
                    A[0].x = fmaf(s0.x, w0.x, A[0].x);  A[0].y = fmaf(s0.y, w0.y, A[0].y);
                    A[1].x = fmaf(s0.x, w0.y, A[1].x);  A[1].y = fmaf(s0.y, w1.x, A[1].y);
                    A[2].x = fmaf(s0.x, w1.x, A[2].x);  A[2].y = fmaf(s0.y, w1.y, A[2].y);
                    A[3].x = fmaf(s0.x, w1.y, A[3].x);  A[3].y = fmaf(s0.y, w2.x, A[3].y);
                    A[4].x = fmaf(s0.x, w2.x, A[4].x);  A[4].y = fmaf(s0.y, w2.y, A[4].y);
                }
                {   // output row 1 uses window row dy+1
                    const float2 w0 = wr[dy + 1][0], w1 = wr[dy + 1][1], w2 = wr[dy + 1][2];
                    float2* A = &acc1[dy * MAXOFF];
                    A[0].x = fmaf(s1.x, w0.x, A[0].x);  A[0].y = fmaf(s1.y, w0.y, A[0].y);
                    A[1].x = fmaf(s1.x, w0.y, A[1].x);  A[1].y = fmaf(s1.y, w1.x, A[1].y);
                    A[2].x = fmaf(s1.x, w1.x, A[2].x);  A[2].y = fmaf(s1.y, w1.y, A[2].y);
                    A[3].x = fmaf(s1.x, w1.y, A[3].x);  A[3].y = fmaf(s1.y, w2.x, A[3].y);
                    A[4].x = fmaf(s1.x, w2.x, A[4].x);  A[4].y = fmaf(s1.y, w2.y, A[4].y);
                }
            }
        }
        __syncthreads();               // everyone done reading lds (round r)
        if (r + 1 < ROUNDS) {
            write_lds();               // waits on round r+1's loads, writes them
#pragma unroll
            for (int j = 0; j < RC; ++j) {
                sc0[j] = sn0[j];
                sc1[j] = sn1[j];
            }
            __syncthreads();           // lds holds round r+1
            if (r + 2 < ROUNDS) {
                issue_c2(r + 2);
                issue_c1(r + 2, sn0, sn1);
            }
        }
    }

    // ---- cross-group reduction (g1..g3 -> g0) + scale + PReLU + store ----
    const float a = pw[0];
    const float inv_c = 1.0f / (float)CHN;
    // two float2 regions: row0 at [0], row1 at [3*OCH*NPT*2] floats
    float2* e0 = (float2*)lds;                       // 3*OCH*64 float2 = 6144 B
    float2* e1 = (float2*)(lds + 3 * OCH * NPT * 2); // same size, total 12288 B

    for (int o0 = 0; o0 < NOFF; o0 += OCH) {
        const int K = (NOFF - o0) < OCH ? (NOFF - o0) : OCH;
        __syncthreads();
        if (g > 0) {
#pragma unroll
            for (int k = 0; k < OCH; ++k)
                if (k < K) {
                    e0[((g - 1) * OCH + k) * NPT + pt] = acc0[o0 + k];
                    e1[((g - 1) * OCH + k) * NPT + pt] = acc1[o0 + k];
                }
        }
        __syncthreads();
        if (g == 0) {
#pragma unroll
            for (int k = 0; k < OCH; ++k) {
                if (k < K) {
                    const int o = o0 + k;
                    float2 u = acc0[o];
                    float2 v = acc1[o];
#pragma unroll
                    for (int q = 0; q < 3; ++q) {
                        float2 ua = e0[(q * OCH + k) * NPT + pt];
                        float2 va = e1[(q * OCH + k) * NPT + pt];
                        u.x += ua.x; u.y += ua.y;
                        v.x += va.x; v.y += va.y;
                    }
                    float ux = u.x * inv_c, uy = u.y * inv_c;
                    float vx = v.x * inv_c, vy = v.y * inv_c;
                    ux = (ux >= 0.f) ? ux : a * ux;
                    uy = (uy >= 0.f) ? uy : a * uy;
                    vx = (vx >= 0.f) ? vx : a * vx;
                    vy = (vy >= 0.f) ? vy : a * vy;
                    float* op = out + (size_t)(b * NOFF + o) * HW
                              + (ty0 + 2 * yg) * WW + tx0 + xh * 2;
                    *(float2*)op        = make_float2(ux, uy);
                    *(float2*)(op + WW) = make_float2(vx, vy);
                }
            }
        }
    }
}

extern "C" void kernel_launch(void* const* d_in, const int* in_sizes, int n_in,
                              void* d_out, int out_size, void* d_ws, size_t ws_size,
                              hipStream_t stream) {
    const float* c1 = (const float*)d_in[0];
    const float* c2 = (const float*)d_in[1];
    const float* pw = (const float*)d_in[2];
    float* out = (float*)d_out;

    dim3 grid((WW / TW) * (HH / TH) * BATCH);   // 5*20*8 = 800 blocks
    dim3 block(NTHREADS);
    costvol_kernel<<<grid, block, 0, stream>>>(c1, c2, pw, out);
}